// Round 1
// baseline (91.826 us; speedup 1.0000x reference)
//
#include <hip/hip_runtime.h>

#define NN 10000   // nodes
#define NE 25000   // edges
#define DF 128     // features

// ---------------- kernels ----------------

__global__ void k_zero2(int* __restrict__ a, int* __restrict__ b, int n) {
    int i = blockIdx.x * blockDim.x + threadIdx.x;
    if (i < n) { a[i] = 0; b[i] = 0; }
}

// new_x[e] = ((x[u]+x[v])*0.5 + edge_attr[e]) * 0.5 ; 32 threads/edge, float4
__global__ void k_newx(const float* __restrict__ x, const float* __restrict__ ea,
                       const int* __restrict__ c0, const int* __restrict__ c1,
                       float* __restrict__ out) {
    int tid = blockIdx.x * blockDim.x + threadIdx.x;
    if (tid >= NE * 32) return;
    int e = tid >> 5, q = tid & 31;
    int u = c0[e], v = c1[e];
    float4 a = ((const float4*)(x + (size_t)u * DF))[q];
    float4 b = ((const float4*)(x + (size_t)v * DF))[q];
    float4 c = ((const float4*)(ea + (size_t)e * DF))[q];
    float4 r;
    r.x = ((a.x + b.x) * 0.5f + c.x) * 0.5f;
    r.y = ((a.y + b.y) * 0.5f + c.y) * 0.5f;
    r.z = ((a.z + b.z) * 0.5f + c.z) * 0.5f;
    r.w = ((a.w + b.w) * 0.5f + c.w) * 0.5f;
    ((float4*)(out + (size_t)e * DF))[q] = r;
}

__global__ void k_count(const int* __restrict__ c0, int* __restrict__ cntNode) {
    int j = blockIdx.x * blockDim.x + threadIdx.x;
    if (j < NE) atomicAdd(&cntNode[c0[j]], 1);
}

// single-workgroup exclusive scan: out[0..n], out[n] = total
__global__ void k_scan_excl(const int* __restrict__ in, int* __restrict__ out, int n) {
    __shared__ int part[1024];
    int t = threadIdx.x;
    int C = (n + 1023) >> 10;
    int lo = t * C; if (lo > n) lo = n;
    int hi = lo + C; if (hi > n) hi = n;
    int s = 0;
    for (int i = lo; i < hi; ++i) s += in[i];
    part[t] = s;
    __syncthreads();
    for (int off = 1; off < 1024; off <<= 1) {
        int add = (t >= off) ? part[t - off] : 0;
        __syncthreads();
        part[t] += add;
        __syncthreads();
    }
    int run = (t == 0) ? 0 : part[t - 1];
    for (int i = lo; i < hi; ++i) { out[i] = run; run += in[i]; }
    if (t == 0) out[n] = part[1023];
}

__global__ void k_fill(const int* __restrict__ c0, const int* __restrict__ bStart,
                       int* __restrict__ fillPos, int* __restrict__ bEdges) {
    int j = blockIdx.x * blockDim.x + threadIdx.x;
    if (j >= NE) return;
    int n = c0[j];
    int p = bStart[n] + atomicAdd(&fillPos[n], 1);
    bEdges[p] = j;
}

// insertion-sort each (tiny) bucket ascending -> deterministic, matches nonzero j-order
__global__ void k_sort(const int* __restrict__ bStart, int* __restrict__ bEdges) {
    int n = blockIdx.x * blockDim.x + threadIdx.x;
    if (n >= NN) return;
    int s = bStart[n], e = bStart[n + 1];
    for (int i = s + 1; i < e; ++i) {
        int key = bEdges[i];
        int j = i - 1;
        while (j >= s && bEdges[j] > key) { bEdges[j + 1] = bEdges[j]; --j; }
        bEdges[j + 1] = key;
    }
}

__global__ void k_cnt_edge(const int* __restrict__ c0, const int* __restrict__ c1,
                           const int* __restrict__ bStart, const int* __restrict__ bEdges,
                           int* __restrict__ cntEdge) {
    int i = blockIdx.x * blockDim.x + threadIdx.x;
    if (i >= NE) return;
    int u = c0[i], v = c1[i];
    int s = bStart[v], e = bStart[v + 1], c = 0;
    for (int p = s; p < e; ++p) {
        int j = bEdges[p];
        if (c1[j] != u) ++c;
    }
    cntEdge[i] = c;
}

__global__ void k_fill_edges(const int* __restrict__ c0, const int* __restrict__ c1,
                             const int* __restrict__ bStart, const int* __restrict__ bEdges,
                             const int* __restrict__ rowStart,
                             float* __restrict__ outRows, float* __restrict__ outCols,
                             int* __restrict__ attrSrc) {
    int i = blockIdx.x * blockDim.x + threadIdx.x;
    if (i >= NE) return;
    int u = c0[i], v = c1[i];
    int s = bStart[v], e = bStart[v + 1];
    int k = rowStart[i];
    for (int p = s; p < e; ++p) {
        int j = bEdges[p];
        if (c1[j] != u) {
            outRows[k] = (float)i;
            outCols[k] = (float)j;
            attrSrc[k] = v;   // lg_edge_attr_idx = col1[i] = v, constant per row i
            ++k;
        }
    }
}

__global__ void k_gather(const float* __restrict__ newx, const int* __restrict__ attrSrc,
                         float* __restrict__ outAttr, int elg) {
    int tid = blockIdx.x * blockDim.x + threadIdx.x;
    if (tid >= elg * 32) return;
    int k = tid >> 5, q = tid & 31;
    int src = attrSrc[k];
    ((float4*)(outAttr + (size_t)k * DF))[q] =
        ((const float4*)(newx + (size_t)src * DF))[q];
}

// ---------------- launch ----------------

extern "C" void kernel_launch(void* const* d_in, const int* in_sizes, int n_in,
                              void* d_out, int out_size, void* d_ws, size_t ws_size,
                              hipStream_t stream) {
    const float* x  = (const float*)d_in[0];
    const float* ea = (const float*)d_in[1];
    const int*   ei = (const int*)d_in[2];
    const int* c0 = ei;        // edge_index[0]
    const int* c1 = ei + NE;   // edge_index[1]

    float* out = (float*)d_out;
    int E_lg = (out_size - NE * DF) / (DF + 2);
    if (E_lg < 0) E_lg = 0;

    float* out_newx = out;                      // NE*DF
    float* out_rows = out + (size_t)NE * DF;    // E_lg
    float* out_cols = out_rows + E_lg;          // E_lg
    float* out_attr = out_cols + E_lg;          // E_lg*DF

    // workspace layout (ints)
    int* ws       = (int*)d_ws;
    int* cntNode  = ws;                         // NN
    int* bStart   = cntNode + NN;               // NN+1
    int* fillPos  = bStart + NN + 1;            // NN
    int* bEdges   = fillPos + NN;               // NE
    int* cntEdge  = bEdges + NE;                // NE
    int* rowStart = cntEdge + NE;               // NE+1
    int* attrSrc  = rowStart + NE + 1;          // E_lg

    k_zero2<<<(NN + 255) / 256, 256, 0, stream>>>(cntNode, fillPos, NN);
    k_newx<<<(NE * 32 + 255) / 256, 256, 0, stream>>>(x, ea, c0, c1, out_newx);
    k_count<<<(NE + 255) / 256, 256, 0, stream>>>(c0, cntNode);
    k_scan_excl<<<1, 1024, 0, stream>>>(cntNode, bStart, NN);
    k_fill<<<(NE + 255) / 256, 256, 0, stream>>>(c0, bStart, fillPos, bEdges);
    k_sort<<<(NN + 255) / 256, 256, 0, stream>>>(bStart, bEdges);
    k_cnt_edge<<<(NE + 255) / 256, 256, 0, stream>>>(c0, c1, bStart, bEdges, cntEdge);
    k_scan_excl<<<1, 1024, 0, stream>>>(cntEdge, rowStart, NE);
    k_fill_edges<<<(NE + 255) / 256, 256, 0, stream>>>(c0, c1, bStart, bEdges, rowStart,
                                                       out_rows, out_cols, attrSrc);
    if (E_lg > 0)
        k_gather<<<(E_lg * 32 + 255) / 256, 256, 0, stream>>>(out_newx, attrSrc, out_attr, E_lg);
}